// Round 3
// baseline (269.308 us; speedup 1.0000x reference)
//
#include <hip/hip_runtime.h>

// BilateralGrid apply.
// R1: LDS fp16 gather (118 us). R2: packed v_pk_fma_f16 (103). R3: padded
// b64 layout (90) — conflicts 3.2e7->2.58e7; hit the b64 floor: 8B-aligned
// gathers only reach 16 bank-pair slots, 64 random lanes -> ~8 extra cy/instr.
// R4: all-b128 gather + full occupancy. (R5 = resubmit; container infra
// failure last round, kernel audited: no OOB, no races, 16B alignment OK.)
//   Split coeffs: A = rows 0,1 (8 halves) in [y][x][z][8], z-stride 16B ->
//   two b128 reads cover z0,z1. B = row 2 duplicated per z-pair:
//   [y][x][zp][8] = {row2[zp], row2[zp+1]} -> one b128 covers both planes.
//   12 b128/px (was 24 b64), all 16B-aligned; start group = (x0+z0)%8 (A),
//   (7*x0+z0)%8 (B) — uniform via x0. LDS = 36864+28672 = 64 KB exactly.
//   BLOCK=1024, 2 blocks/CU -> 32 waves/CU (was 24). Numerics unchanged.

typedef _Float16 h4 __attribute__((ext_vector_type(4)));
typedef _Float16 h8 __attribute__((ext_vector_type(8)));

#define BLOCK 1024

// A: coeffs 0..7: [y][x][z][8] halves. XSA=72 (9*8, group stride 1 mod 8),
// YSA=16*72=1152. Total 16*1152 = 18432 halves = 36864 B.
#define XSA 72
#define YSA 1152
#define NA  18432
// B: coeffs 8..11, z-pair duplicated: [y][x][zp][8], zp=0..6 (+1 slack row).
// XSB=56 (7*8, group stride 7 mod 8), YSB=16*56=896. 16*896=14336 h = 28672 B.
#define XSB 56
#define YSB 896
#define NB  14336

__global__ __launch_bounds__(BLOCK, 8) void bilateral_apply(
    const float* __restrict__ pixels,
    const float* __restrict__ coords,
    const float* __restrict__ grid,
    float* __restrict__ out,
    int n4)
{
    __shared__ alignas(16) _Float16 gA[NA];  // 36864 B
    __shared__ alignas(16) _Float16 gB[NB];  // 28672 B  (total exactly 64 KB)

    // Cooperative stage: fp32 grid -> fp16 LDS, split layout.
    for (int cell = threadIdx.x; cell < 2048; cell += BLOCK) {
        int y = cell >> 7;
        int x = (cell >> 3) & 15;
        int z = cell & 7;
        const float4* src = (const float4*)(grid + (long long)cell * 12);
        float4 v0 = src[0], v1 = src[1], v2 = src[2];
        h8 a = { (_Float16)v0.x, (_Float16)v0.y, (_Float16)v0.z, (_Float16)v0.w,
                 (_Float16)v1.x, (_Float16)v1.y, (_Float16)v1.z, (_Float16)v1.w };
        *(h8*)(gA + y * YSA + x * XSA + z * 8) = a;   // 16B aligned
        h4 b = { (_Float16)v2.x, (_Float16)v2.y, (_Float16)v2.z, (_Float16)v2.w };
        _Float16* bb = gB + y * YSB + x * XSB;
        if (z <= 6) *(h4*)(bb + z * 8) = b;           // lo half of pair z
        if (z >= 1) *(h4*)(bb + (z - 1) * 8 + 4) = b; // hi half of pair z-1
    }
    __syncthreads();

    const int stride = gridDim.x * BLOCK;
    for (int t = blockIdx.x * BLOCK + threadIdx.x; t < n4; t += stride) {
        long long base = (long long)t * 4;  // first pixel of this quad

        const float* pp = pixels + base * 3;
        const float* cp = coords + base * 2;
        float4 pa = *(const float4*)(pp + 0);
        float4 pb = *(const float4*)(pp + 4);
        float4 pc = *(const float4*)(pp + 8);
        float4 ca = *(const float4*)(cp + 0);
        float4 cb = *(const float4*)(cp + 4);

        float R[4]  = {pa.x, pa.w, pb.z, pc.y};
        float G[4]  = {pa.y, pb.x, pb.w, pc.z};
        float Bc[4] = {pa.z, pb.y, pc.x, pc.w};
        float CX[4] = {ca.x, ca.z, cb.x, cb.z};
        float CY[4] = {ca.y, ca.w, cb.y, cb.w};

        float O[12];

        #pragma unroll
        for (int k = 0; k < 4; ++k) {
            float r = R[k], g = G[k], b = Bc[k];
            float guide = 0.2126f * r + 0.7152f * g + 0.0722f * b;

            float gx = fminf(fmaxf(CX[k] * 15.0f, 0.0f), 14.999f);
            float gy = fminf(fmaxf(CY[k] * 15.0f, 0.0f), 14.999f);
            float gz = fminf(fminf(fmaxf(guide, 0.0f), 1.0f) * 7.0f, 6.999f);

            int x0 = (int)gx, y0 = (int)gy, z0 = (int)gz;
            float fx = gx - (float)x0;
            float fy = gy - (float)y0;
            float fz = gz - (float)z0;

            int abase = y0 * YSA + x0 * XSA + z0 * 8;
            int bbase = y0 * YSB + x0 * XSB + z0 * 8;
            const int aoff[4] = {0, XSA, YSA, YSA + XSA};
            const int boff[4] = {0, XSB, YSB, YSB + XSB};
            float wz0 = 1.0f - fz, wz1 = fz;
            float cw[4] = {(1.0f - fy) * (1.0f - fx), (1.0f - fy) * fx,
                           fy * (1.0f - fx),           fy * fx};

            h8 accA = (h8)(_Float16)0.0f;   // rows 0,1
            h4 accB = (h4)(_Float16)0.0f;   // row 2

            #pragma unroll
            for (int c = 0; c < 4; ++c) {
                const h8* qa = (const h8*)(gA + abase + aoff[c]);  // 16B aligned
                h8 alo = qa[0];   // rows 0,1 @ z0
                h8 ahi = qa[1];   // rows 0,1 @ z1
                h8 qb  = *(const h8*)(gB + bbase + boff[c]);       // row2 @ z0,z1
                _Float16 u0 = (_Float16)(cw[c] * wz0);
                _Float16 u1 = (_Float16)(cw[c] * wz1);
                h8 u0v8 = {u0, u0, u0, u0, u0, u0, u0, u0};
                h8 u1v8 = {u1, u1, u1, u1, u1, u1, u1, u1};
                accA = alo * u0v8 + (ahi * u1v8 + accA);           // v_pk_fma_f16
                h4 blo = __builtin_shufflevector(qb, qb, 0, 1, 2, 3);
                h4 bhi = __builtin_shufflevector(qb, qb, 4, 5, 6, 7);
                h4 u0v4 = {u0, u0, u0, u0};
                h4 u1v4 = {u1, u1, u1, u1};
                accB = blo * u0v4 + (bhi * u1v4 + accB);
            }

            h4 acc0 = __builtin_shufflevector(accA, accA, 0, 1, 2, 3);
            h4 acc1 = __builtin_shufflevector(accA, accA, 4, 5, 6, 7);

            O[3 * k + 0] = fmaf((float)acc0.x, r, fmaf((float)acc0.y, g,
                           fmaf((float)acc0.z, b, (float)acc0.w)));
            O[3 * k + 1] = fmaf((float)acc1.x, r, fmaf((float)acc1.y, g,
                           fmaf((float)acc1.z, b, (float)acc1.w)));
            O[3 * k + 2] = fmaf((float)accB.x, r, fmaf((float)accB.y, g,
                           fmaf((float)accB.z, b, (float)accB.w)));
        }

        float* op = out + base * 3;
        *(float4*)(op + 0) = make_float4(O[0], O[1], O[2],  O[3]);
        *(float4*)(op + 4) = make_float4(O[4], O[5], O[6],  O[7]);
        *(float4*)(op + 8) = make_float4(O[8], O[9], O[10], O[11]);
    }
}

extern "C" void kernel_launch(void* const* d_in, const int* in_sizes, int n_in,
                              void* d_out, int out_size, void* d_ws, size_t ws_size,
                              hipStream_t stream) {
    const float* pixels = (const float*)d_in[0];
    const float* coords = (const float*)d_in[1];
    const float* grid   = (const float*)d_in[2];
    float* out = (float*)d_out;

    int npix = in_sizes[0] / 3;   // 8,294,400 (divisible by 4)
    int n4   = npix / 4;          // 2,073,600 quads
    // 64 KB LDS/block, 1024 thr => 2 blocks/CU = 32 waves/CU (full).
    // 512 = 2*256 CUs: exactly one resident block set, single staging each.
    int nblk = 512;
    bilateral_apply<<<nblk, BLOCK, 0, stream>>>(pixels, coords, grid, out, n4);
}

// Round 4
// 234.283 us; speedup vs baseline: 1.1495x; 1.1495x over previous
//
#include <hip/hip_runtime.h>

// BilateralGrid apply.
// R1: LDS fp16 gather (118 us). R2: packed v_pk_fma_f16 (103). R3: padded
// b64 layout (90) — conflicts 3.2e7->2.58e7 (b64 floor). R4: all-b128
// gather, BLOCK=1024: conflicts 1.295e7 as predicted BUT __launch_bounds__
// (1024,8) forced VGPR 40->32 => scratch spills => WRITE_SIZE 99->285 MB,
// FETCH 82->142 MB, dur 127 us (HBM-bound on spill traffic).
// R6: identical kernel, launch_bounds(1024) WITHOUT the min-waves clamp —
// let the allocator take ~48 VGPR (<=64 still allows 8 waves/EU; LDS caps
// us at 2 blocks/CU = 32 waves anyway). No other changes.
//   Layout recap: A = rows 0,1 (8 halves) [y][x][z][8], z-stride 16B -> two
//   b128 cover z0,z1. B = row 2 z-pair duplicated [y][x][zp][8] -> one b128
//   covers both planes. 12 b128/px, all 16B-aligned; start group (x0+z0)%8
//   (A), (7*x0+z0)%8 (B). LDS = 36864+28672 = 64 KB exactly.

typedef _Float16 h4 __attribute__((ext_vector_type(4)));
typedef _Float16 h8 __attribute__((ext_vector_type(8)));

#define BLOCK 1024

// A: coeffs 0..7: [y][x][z][8] halves. XSA=72 (9*8, group stride 1 mod 8),
// YSA=16*72=1152. Total 16*1152 = 18432 halves = 36864 B.
#define XSA 72
#define YSA 1152
#define NA  18432
// B: coeffs 8..11, z-pair duplicated: [y][x][zp][8], zp=0..6 (+1 slack row).
// XSB=56 (7*8, group stride 7 mod 8), YSB=16*56=896. 16*896=14336 h = 28672 B.
#define XSB 56
#define YSB 896
#define NB  14336

__global__ __launch_bounds__(BLOCK) void bilateral_apply(
    const float* __restrict__ pixels,
    const float* __restrict__ coords,
    const float* __restrict__ grid,
    float* __restrict__ out,
    int n4)
{
    __shared__ alignas(16) _Float16 gA[NA];  // 36864 B
    __shared__ alignas(16) _Float16 gB[NB];  // 28672 B  (total exactly 64 KB)

    // Cooperative stage: fp32 grid -> fp16 LDS, split layout.
    for (int cell = threadIdx.x; cell < 2048; cell += BLOCK) {
        int y = cell >> 7;
        int x = (cell >> 3) & 15;
        int z = cell & 7;
        const float4* src = (const float4*)(grid + (long long)cell * 12);
        float4 v0 = src[0], v1 = src[1], v2 = src[2];
        h8 a = { (_Float16)v0.x, (_Float16)v0.y, (_Float16)v0.z, (_Float16)v0.w,
                 (_Float16)v1.x, (_Float16)v1.y, (_Float16)v1.z, (_Float16)v1.w };
        *(h8*)(gA + y * YSA + x * XSA + z * 8) = a;   // 16B aligned
        h4 b = { (_Float16)v2.x, (_Float16)v2.y, (_Float16)v2.z, (_Float16)v2.w };
        _Float16* bb = gB + y * YSB + x * XSB;
        if (z <= 6) *(h4*)(bb + z * 8) = b;           // lo half of pair z
        if (z >= 1) *(h4*)(bb + (z - 1) * 8 + 4) = b; // hi half of pair z-1
    }
    __syncthreads();

    const int stride = gridDim.x * BLOCK;
    for (int t = blockIdx.x * BLOCK + threadIdx.x; t < n4; t += stride) {
        long long base = (long long)t * 4;  // first pixel of this quad

        const float* pp = pixels + base * 3;
        const float* cp = coords + base * 2;
        float4 pa = *(const float4*)(pp + 0);
        float4 pb = *(const float4*)(pp + 4);
        float4 pc = *(const float4*)(pp + 8);
        float4 ca = *(const float4*)(cp + 0);
        float4 cb = *(const float4*)(cp + 4);

        float R[4]  = {pa.x, pa.w, pb.z, pc.y};
        float G[4]  = {pa.y, pb.x, pb.w, pc.z};
        float Bc[4] = {pa.z, pb.y, pc.x, pc.w};
        float CX[4] = {ca.x, ca.z, cb.x, cb.z};
        float CY[4] = {ca.y, ca.w, cb.y, cb.w};

        float O[12];

        #pragma unroll
        for (int k = 0; k < 4; ++k) {
            float r = R[k], g = G[k], b = Bc[k];
            float guide = 0.2126f * r + 0.7152f * g + 0.0722f * b;

            float gx = fminf(fmaxf(CX[k] * 15.0f, 0.0f), 14.999f);
            float gy = fminf(fmaxf(CY[k] * 15.0f, 0.0f), 14.999f);
            float gz = fminf(fminf(fmaxf(guide, 0.0f), 1.0f) * 7.0f, 6.999f);

            int x0 = (int)gx, y0 = (int)gy, z0 = (int)gz;
            float fx = gx - (float)x0;
            float fy = gy - (float)y0;
            float fz = gz - (float)z0;

            int abase = y0 * YSA + x0 * XSA + z0 * 8;
            int bbase = y0 * YSB + x0 * XSB + z0 * 8;
            const int aoff[4] = {0, XSA, YSA, YSA + XSA};
            const int boff[4] = {0, XSB, YSB, YSB + XSB};
            float wz0 = 1.0f - fz, wz1 = fz;
            float cw[4] = {(1.0f - fy) * (1.0f - fx), (1.0f - fy) * fx,
                           fy * (1.0f - fx),           fy * fx};

            h8 accA = (h8)(_Float16)0.0f;   // rows 0,1
            h4 accB = (h4)(_Float16)0.0f;   // row 2

            #pragma unroll
            for (int c = 0; c < 4; ++c) {
                const h8* qa = (const h8*)(gA + abase + aoff[c]);  // 16B aligned
                h8 alo = qa[0];   // rows 0,1 @ z0
                h8 ahi = qa[1];   // rows 0,1 @ z1
                h8 qb  = *(const h8*)(gB + bbase + boff[c]);       // row2 @ z0,z1
                _Float16 u0 = (_Float16)(cw[c] * wz0);
                _Float16 u1 = (_Float16)(cw[c] * wz1);
                h8 u0v8 = {u0, u0, u0, u0, u0, u0, u0, u0};
                h8 u1v8 = {u1, u1, u1, u1, u1, u1, u1, u1};
                accA = alo * u0v8 + (ahi * u1v8 + accA);           // v_pk_fma_f16
                h4 blo = __builtin_shufflevector(qb, qb, 0, 1, 2, 3);
                h4 bhi = __builtin_shufflevector(qb, qb, 4, 5, 6, 7);
                h4 u0v4 = {u0, u0, u0, u0};
                h4 u1v4 = {u1, u1, u1, u1};
                accB = blo * u0v4 + (bhi * u1v4 + accB);
            }

            h4 acc0 = __builtin_shufflevector(accA, accA, 0, 1, 2, 3);
            h4 acc1 = __builtin_shufflevector(accA, accA, 4, 5, 6, 7);

            O[3 * k + 0] = fmaf((float)acc0.x, r, fmaf((float)acc0.y, g,
                           fmaf((float)acc0.z, b, (float)acc0.w)));
            O[3 * k + 1] = fmaf((float)acc1.x, r, fmaf((float)acc1.y, g,
                           fmaf((float)acc1.z, b, (float)acc1.w)));
            O[3 * k + 2] = fmaf((float)accB.x, r, fmaf((float)accB.y, g,
                           fmaf((float)accB.z, b, (float)accB.w)));
        }

        float* op = out + base * 3;
        *(float4*)(op + 0) = make_float4(O[0], O[1], O[2],  O[3]);
        *(float4*)(op + 4) = make_float4(O[4], O[5], O[6],  O[7]);
        *(float4*)(op + 8) = make_float4(O[8], O[9], O[10], O[11]);
    }
}

extern "C" void kernel_launch(void* const* d_in, const int* in_sizes, int n_in,
                              void* d_out, int out_size, void* d_ws, size_t ws_size,
                              hipStream_t stream) {
    const float* pixels = (const float*)d_in[0];
    const float* coords = (const float*)d_in[1];
    const float* grid   = (const float*)d_in[2];
    float* out = (float*)d_out;

    int npix = in_sizes[0] / 3;   // 8,294,400 (divisible by 4)
    int n4   = npix / 4;          // 2,073,600 quads
    // 64 KB LDS/block => 2 blocks/CU. 512 = 2*256 CUs: one resident set.
    int nblk = 512;
    bilateral_apply<<<nblk, BLOCK, 0, stream>>>(pixels, coords, grid, out, n4);
}

// Round 5
// 230.907 us; speedup vs baseline: 1.1663x; 1.0146x over previous
//
#include <hip/hip_runtime.h>

// BilateralGrid apply.
// R1: LDS fp16 gather (118 us). R2: packed v_pk_fma_f16 (103). R3: padded
// b64 layout (90us; conflicts 3.2e7->2.58e7, b64 floor). R4: b128 split
// layout + launch_bounds(1024,8): conflicts 1.295e7 but VGPR forced to 32 =>
// scratch spills => 127us. R6: same minus the waves clamp: VGPR 40, no
// spills, conflicts 1.295e7, but 103us — LATENCY-bound: LDS pipe only 40%
// busy (41us), VALU 24%, HBM 23%. 40 VGPRs => compiler can't hoist next
// iteration's global loads => ~800cy exposed vmcnt per iteration, all 32
// waves convoying.
// R7: software pipeline. (a) first quad's loads issued BEFORE grid staging
// (latency hides under stage+barrier); (b) in-loop prefetch of t+stride's
// 5 float4s pinned above compute via sched_barrier(0); register rotation;
// loop unroll disabled to hold VGPR ~60 (<=64 keeps 2x1024 blocks/CU).
// Layout recap (unchanged): A = rows 0,1 [y][x][z][8]h, XSA=72, two b128
// cover z0,z1; B = row 2 z-pair duplicated [y][x][zp][8]h, XSB=56, one b128
// covers both planes. 12 b128/px, 16B-aligned, start group (x0+z0)%8 /
// (7x0+z0)%8. LDS = 36864+28672 = 64 KB exactly, 2 blocks/CU = 32 waves.

typedef _Float16 h4 __attribute__((ext_vector_type(4)));
typedef _Float16 h8 __attribute__((ext_vector_type(8)));

#define BLOCK 1024

#define XSA 72
#define YSA 1152
#define NA  18432
#define XSB 56
#define YSB 896
#define NB  14336

__global__ __launch_bounds__(BLOCK) void bilateral_apply(
    const float* __restrict__ pixels,
    const float* __restrict__ coords,
    const float* __restrict__ grid,
    float* __restrict__ out,
    int n4)
{
    __shared__ alignas(16) _Float16 gA[NA];  // 36864 B
    __shared__ alignas(16) _Float16 gB[NB];  // 28672 B  (total exactly 64 KB)

    const int stride = gridDim.x * BLOCK;
    int t = blockIdx.x * BLOCK + threadIdx.x;

    // ---- First quad's loads, issued BEFORE staging: ~900cy HBM latency
    // hides under the staging loop + barrier. (grid=512 blocks => every
    // initial t < n4.)
    long long base = (long long)t * 4;
    const float* pp = pixels + base * 3;
    const float* cp = coords + base * 2;
    float4 pa = *(const float4*)(pp + 0);
    float4 pb = *(const float4*)(pp + 4);
    float4 pc = *(const float4*)(pp + 8);
    float4 ca = *(const float4*)(cp + 0);
    float4 cb = *(const float4*)(cp + 4);

    // ---- Cooperative stage: fp32 grid -> fp16 LDS, split layout.
    for (int cell = threadIdx.x; cell < 2048; cell += BLOCK) {
        int y = cell >> 7;
        int x = (cell >> 3) & 15;
        int z = cell & 7;
        const float4* src = (const float4*)(grid + (long long)cell * 12);
        float4 v0 = src[0], v1 = src[1], v2 = src[2];
        h8 a = { (_Float16)v0.x, (_Float16)v0.y, (_Float16)v0.z, (_Float16)v0.w,
                 (_Float16)v1.x, (_Float16)v1.y, (_Float16)v1.z, (_Float16)v1.w };
        *(h8*)(gA + y * YSA + x * XSA + z * 8) = a;   // 16B aligned
        h4 b = { (_Float16)v2.x, (_Float16)v2.y, (_Float16)v2.z, (_Float16)v2.w };
        _Float16* bb = gB + y * YSB + x * XSB;
        if (z <= 6) *(h4*)(bb + z * 8) = b;           // lo half of pair z
        if (z >= 1) *(h4*)(bb + (z - 1) * 8 + 4) = b; // hi half of pair z-1
    }
    __syncthreads();

    #pragma clang loop unroll(disable)
    while (true) {
        // ---- Prefetch next quad while this one computes.
        int tn = t + stride;
        bool more = tn < n4;
        float4 npa, npb, npc, nca, ncb;
        if (more) {
            long long nbase = (long long)tn * 4;
            const float* npp = pixels + nbase * 3;
            const float* ncp = coords + nbase * 2;
            npa = *(const float4*)(npp + 0);
            npb = *(const float4*)(npp + 4);
            npc = *(const float4*)(npp + 8);
            nca = *(const float4*)(ncp + 0);
            ncb = *(const float4*)(ncp + 4);
        }
        __builtin_amdgcn_sched_barrier(0);  // pin prefetch issue above compute

        float R[4]  = {pa.x, pa.w, pb.z, pc.y};
        float G[4]  = {pa.y, pb.x, pb.w, pc.z};
        float Bc[4] = {pa.z, pb.y, pc.x, pc.w};
        float CX[4] = {ca.x, ca.z, cb.x, cb.z};
        float CY[4] = {ca.y, ca.w, cb.y, cb.w};

        float O[12];

        #pragma unroll
        for (int k = 0; k < 4; ++k) {
            float r = R[k], g = G[k], b = Bc[k];
            float guide = 0.2126f * r + 0.7152f * g + 0.0722f * b;

            float gx = fminf(fmaxf(CX[k] * 15.0f, 0.0f), 14.999f);
            float gy = fminf(fmaxf(CY[k] * 15.0f, 0.0f), 14.999f);
            float gz = fminf(fminf(fmaxf(guide, 0.0f), 1.0f) * 7.0f, 6.999f);

            int x0 = (int)gx, y0 = (int)gy, z0 = (int)gz;
            float fx = gx - (float)x0;
            float fy = gy - (float)y0;
            float fz = gz - (float)z0;

            int abase = y0 * YSA + x0 * XSA + z0 * 8;
            int bbase = y0 * YSB + x0 * XSB + z0 * 8;
            const int aoff[4] = {0, XSA, YSA, YSA + XSA};
            const int boff[4] = {0, XSB, YSB, YSB + XSB};
            float wz0 = 1.0f - fz, wz1 = fz;
            float cw[4] = {(1.0f - fy) * (1.0f - fx), (1.0f - fy) * fx,
                           fy * (1.0f - fx),           fy * fx};

            h8 accA = (h8)(_Float16)0.0f;   // rows 0,1
            h4 accB = (h4)(_Float16)0.0f;   // row 2

            #pragma unroll
            for (int c = 0; c < 4; ++c) {
                const h8* qa = (const h8*)(gA + abase + aoff[c]);  // 16B aligned
                h8 alo = qa[0];   // rows 0,1 @ z0
                h8 ahi = qa[1];   // rows 0,1 @ z1
                h8 qb  = *(const h8*)(gB + bbase + boff[c]);       // row2 @ z0,z1
                _Float16 u0 = (_Float16)(cw[c] * wz0);
                _Float16 u1 = (_Float16)(cw[c] * wz1);
                h8 u0v8 = {u0, u0, u0, u0, u0, u0, u0, u0};
                h8 u1v8 = {u1, u1, u1, u1, u1, u1, u1, u1};
                accA = alo * u0v8 + (ahi * u1v8 + accA);           // v_pk_fma_f16
                h4 blo = __builtin_shufflevector(qb, qb, 0, 1, 2, 3);
                h4 bhi = __builtin_shufflevector(qb, qb, 4, 5, 6, 7);
                h4 u0v4 = {u0, u0, u0, u0};
                h4 u1v4 = {u1, u1, u1, u1};
                accB = blo * u0v4 + (bhi * u1v4 + accB);
            }

            h4 acc0 = __builtin_shufflevector(accA, accA, 0, 1, 2, 3);
            h4 acc1 = __builtin_shufflevector(accA, accA, 4, 5, 6, 7);

            O[3 * k + 0] = fmaf((float)acc0.x, r, fmaf((float)acc0.y, g,
                           fmaf((float)acc0.z, b, (float)acc0.w)));
            O[3 * k + 1] = fmaf((float)acc1.x, r, fmaf((float)acc1.y, g,
                           fmaf((float)acc1.z, b, (float)acc1.w)));
            O[3 * k + 2] = fmaf((float)accB.x, r, fmaf((float)accB.y, g,
                           fmaf((float)accB.z, b, (float)accB.w)));
        }

        float* op = out + base * 3;
        *(float4*)(op + 0) = make_float4(O[0], O[1], O[2],  O[3]);
        *(float4*)(op + 4) = make_float4(O[4], O[5], O[6],  O[7]);
        *(float4*)(op + 8) = make_float4(O[8], O[9], O[10], O[11]);

        if (!more) break;
        pa = npa; pb = npb; pc = npc; ca = nca; cb = ncb;
        t = tn;
        base = (long long)t * 4;
    }
}

extern "C" void kernel_launch(void* const* d_in, const int* in_sizes, int n_in,
                              void* d_out, int out_size, void* d_ws, size_t ws_size,
                              hipStream_t stream) {
    const float* pixels = (const float*)d_in[0];
    const float* coords = (const float*)d_in[1];
    const float* grid   = (const float*)d_in[2];
    float* out = (float*)d_out;

    int npix = in_sizes[0] / 3;   // 8,294,400 (divisible by 4)
    int n4   = npix / 4;          // 2,073,600 quads
    // 64 KB LDS/block => 2 blocks/CU = 32 waves/CU. 512 = 2*256 CUs.
    int nblk = 512;
    bilateral_apply<<<nblk, BLOCK, 0, stream>>>(pixels, coords, grid, out, n4);
}